// Round 3
// baseline (352.039 us; speedup 1.0000x reference)
//
#include <hip/hip_runtime.h>
#include <hip/hip_bf16.h>

// Problem dims (fixed)
#define B_   4
#define C1_  512
#define T_   256
#define H_   64
#define TH_  (T_*H_)     // 16384
#define AUX_ 256
#define OUT_ 512
#define INF_ 768         // C1+AUX
#define BK   32
#define THB  64
#define WSTR 40          // padded LDS row stride (bf16 elems): 80B, b128-aligned, ~2-way banks

typedef __attribute__((ext_vector_type(8))) short bf16x8;
typedef __attribute__((ext_vector_type(4))) float f32x4;

__device__ __forceinline__ ushort bf16u(float f) {
    __hip_bfloat16 h = __float2bfloat16(f);
    return *reinterpret_cast<ushort*>(&h);
}

// prep1: W[:, :512] fp32 -> bf16 (Wbf[o][c], contiguous 512)
__global__ void wconv_kernel(const float* __restrict__ W, ushort* __restrict__ Wbf) {
    int idx = (blockIdx.x * 256 + threadIdx.x) * 4;   // 256 blocks x 256 thr x 4 = 262144
    int o = idx >> 9, c = idx & 511;
    const float4 v = *(const float4*)(W + (size_t)o * INF_ + c);
    ushort4 u = make_ushort4(bf16u(v.x), bf16u(v.y), bf16u(v.z), bf16u(v.w));
    *(ushort4*)(Wbf + idx) = u;
}

// prep2: sW[b][o] = bias[o] + sum_c s[b][c] * W[o][512+c]
__global__ void sw_kernel(const float* __restrict__ s, const float* __restrict__ W,
                          const float* __restrict__ bias, float* __restrict__ sW) {
    __shared__ float sl[AUX_];
    int b = blockIdx.x, o = threadIdx.x;
    for (int c = threadIdx.x; c < AUX_; c += 512) sl[c] = s[b * AUX_ + c];
    __syncthreads();
    float acc = bias[o];
    const float* wr = W + (size_t)o * INF_ + C1_;
    #pragma unroll 8
    for (int c = 0; c < AUX_; c += 4) {
        float4 w = *(const float4*)(wr + c);
        acc += sl[c] * w.x + sl[c+1] * w.y + sl[c+2] * w.z + sl[c+3] * w.w;
    }
    sW[b * OUT_ + o] = acc;
}

// main fused kernel: GEMM(512xTHB, K=512) + sW-bias + PReLU + LayerNorm(o) + residual
__global__ __launch_bounds__(512) void fused_kernel(
    const float* __restrict__ X, const ushort* __restrict__ Wbf,
    const float* __restrict__ sW, const float* __restrict__ a2p,
    const float* __restrict__ ln2w, const float* __restrict__ ln2b,
    float* __restrict__ Yout)
{
    __shared__ __align__(16) ushort Ws[C1_ * WSTR];   // 40960 B
    __shared__ __align__(16) ushort Xs[THB * WSTR];   //  5120 B
    __shared__ float red[8][THB][2];                  //  4096 B

    const int tid  = threadIdx.x;
    const int lane = tid & 63;
    const int w    = tid >> 6;          // wave 0..7 -> o range [w*64, w*64+64)
    const int b    = blockIdx.y;
    const int th0  = blockIdx.x * THB;
    const float* xb = X + (size_t)b * C1_ * TH_;

    const int l15 = lane & 15;
    const int lhi = lane >> 4;

    f32x4 acc[4][4] = {};   // wave tile 64(o) x 64(col): 4x4 fragments of 16x16

    for (int kk = 0; kk < C1_ / BK; ++kk) {
        const int kc = kk * BK;
        // ---- stage W tile: 512 x 32 bf16 (from pre-converted Wbf) ----
        #pragma unroll
        for (int it = 0; it < 4; ++it) {
            int slot = tid + it * 512;          // 2048 chunks of 8 bf16
            int r = slot >> 2, q = slot & 3;
            const uint4 v = *(const uint4*)(Wbf + (size_t)r * C1_ + kc + q * 8);
            *(uint4*)(&Ws[r * WSTR + q * 8]) = v;
        }
        // ---- stage X tile: 32(c) x 64(col) fp32 -> bf16, transposed to Xs[col][c] ----
        {
            int i = tid >> 4, j4 = tid & 15;
            const float4 v = *(const float4*)(xb + (size_t)(kc + i) * TH_ + th0 + j4 * 4);
            Xs[(j4 * 4 + 0) * WSTR + i] = bf16u(v.x);
            Xs[(j4 * 4 + 1) * WSTR + i] = bf16u(v.y);
            Xs[(j4 * 4 + 2) * WSTR + i] = bf16u(v.z);
            Xs[(j4 * 4 + 3) * WSTR + i] = bf16u(v.w);
        }
        __syncthreads();
        // ---- fragments + MFMA ----
        bf16x8 af[4], bfr[4];
        #pragma unroll
        for (int fm = 0; fm < 4; ++fm)
            af[fm] = *(const bf16x8*)(&Ws[(w * 64 + fm * 16 + l15) * WSTR + lhi * 8]);
        #pragma unroll
        for (int fn = 0; fn < 4; ++fn)
            bfr[fn] = *(const bf16x8*)(&Xs[(fn * 16 + l15) * WSTR + lhi * 8]);
        #pragma unroll
        for (int fm = 0; fm < 4; ++fm) {
            #pragma unroll
            for (int fn = 0; fn < 4; ++fn)
                acc[fm][fn] = __builtin_amdgcn_mfma_f32_16x16x32_bf16(
                    af[fm], bfr[fn], acc[fm][fn], 0, 0, 0);
        }
        __syncthreads();
    }

    // ---- epilogue: +sW, PReLU, LN stats ----
    const float a2 = a2p[0];
    const int obase = w * 64;
    float swv[4][4];
    #pragma unroll
    for (int fm = 0; fm < 4; ++fm)
        #pragma unroll
        for (int r = 0; r < 4; ++r)
            swv[fm][r] = sW[b * OUT_ + obase + fm * 16 + lhi * 4 + r];

    float s1[4] = {0,0,0,0}, s2[4] = {0,0,0,0};
    #pragma unroll
    for (int fm = 0; fm < 4; ++fm) {
        #pragma unroll
        for (int fn = 0; fn < 4; ++fn) {
            #pragma unroll
            for (int r = 0; r < 4; ++r) {
                float z = acc[fm][fn][r] + swv[fm][r];
                float v = z >= 0.f ? z : a2 * z;
                acc[fm][fn][r] = v;
                s1[fn] += v; s2[fn] += v * v;
            }
        }
    }
    // reduce over the 4 lhi groups (same col, different o) within the wave
    #pragma unroll
    for (int fn = 0; fn < 4; ++fn) {
        s1[fn] += __shfl_xor(s1[fn], 16, 64);
        s2[fn] += __shfl_xor(s2[fn], 16, 64);
        s1[fn] += __shfl_xor(s1[fn], 32, 64);
        s2[fn] += __shfl_xor(s2[fn], 32, 64);
    }
    if (lane < 16) {
        #pragma unroll
        for (int fn = 0; fn < 4; ++fn) {
            red[w][fn * 16 + lane][0] = s1[fn];
            red[w][fn * 16 + lane][1] = s2[fn];
        }
    }
    __syncthreads();
    float mean[4], rstd[4];
    #pragma unroll
    for (int fn = 0; fn < 4; ++fn) {
        float t1 = 0.f, t2 = 0.f;
        #pragma unroll
        for (int ww = 0; ww < 8; ++ww) {
            t1 += red[ww][fn * 16 + l15][0];
            t2 += red[ww][fn * 16 + l15][1];
        }
        float mu = t1 * (1.0f / OUT_);
        mean[fn] = mu;
        float var = t2 * (1.0f / OUT_) - mu * mu;
        rstd[fn] = rsqrtf(var + 1e-8f);
    }
    // ---- output: residual + LN affine ----
    #pragma unroll
    for (int fm = 0; fm < 4; ++fm) {
        #pragma unroll
        for (int r = 0; r < 4; ++r) {
            int o = obase + fm * 16 + lhi * 4 + r;
            float wo = ln2w[o], bo = ln2b[o];
            const float* xrow = xb + (size_t)o * TH_ + th0;
            float* yrow = Yout + ((size_t)b * OUT_ + o) * TH_ + th0;
            #pragma unroll
            for (int fn = 0; fn < 4; ++fn) {
                int col = fn * 16 + l15;
                float resid = xrow[col];
                yrow[col] = resid + (acc[fm][fn][r] - mean[fn]) * rstd[fn] * wo + bo;
            }
        }
    }
}

extern "C" void kernel_launch(void* const* d_in, const int* in_sizes, int n_in,
                              void* d_out, int out_size, void* d_ws, size_t ws_size,
                              hipStream_t stream) {
    const float* x    = (const float*)d_in[0];
    const float* s    = (const float*)d_in[1];
    const float* W    = (const float*)d_in[5];
    const float* bias = (const float*)d_in[6];
    const float* a2   = (const float*)d_in[7];
    const float* ln2w = (const float*)d_in[8];
    const float* ln2b = (const float*)d_in[9];
    float* out = (float*)d_out;

    ushort* Wbf = (ushort*)d_ws;                           // 512 KB
    float*  sW  = (float*)((char*)d_ws + C1_ * OUT_ * 2);  // 8 KB

    wconv_kernel<<<256, 256, 0, stream>>>(W, Wbf);
    sw_kernel<<<B_, 512, 0, stream>>>(s, W, bias, sW);
    dim3 grid(TH_ / THB, B_);
    fused_kernel<<<grid, 512, 0, stream>>>(x, Wbf, sW, a2, ln2w, ln2b, out);
}